// Round 14
// baseline (43.594 us; speedup 1.0000x reference)
//
#include <hip/hip_runtime.h>

typedef float f32x4 __attribute__((ext_vector_type(4)));
typedef short s16x8 __attribute__((ext_vector_type(8)));
typedef unsigned int u32;
typedef u32 u32x2 __attribute__((ext_vector_type(2)));
typedef u32 u32x4 __attribute__((ext_vector_type(4)));

#define NB 8
#define HH 64
#define WW 32
#define CC 64
#define P2N 1680   // dense patches (input_2) = M
#define P1N 420    // strided patches (input_1) = N
#define OUTC 28
#define P1C 14
#define KF 1600
#define NP2 (NB*P2N)
#define NP1 (NB*P1N)
#define NELEM (NB*HH*WW*CC)   // 1048576
#define NPIX (NB*HH*WW)       // 16384

#define BM 256
#define BN 128
#define AROWS 14              // max y2-span(10) + PATCH-1
#define BROWS 23              // max y1-span(19) + PATCH-1
#define ABYTES (AROWS*32*128) // 57344
#define BBYTES (BROWS*32*128) // 94208

__device__ __forceinline__ u32 pack2_bf16(float x, float y) {
    u32 ux = __builtin_bit_cast(u32, x);
    u32 uy = __builtin_bit_cast(u32, y);
    ux = (ux + 0x7FFFu + ((ux >> 16) & 1u)) >> 16;
    uy = (uy + 0x7FFFu + ((uy >> 16) & 1u)) & 0xFFFF0000u;
    return (ux & 0xFFFFu) | uy;
}

__device__ __forceinline__ void glds16(const void* g, void* l) {
    __builtin_amdgcn_global_load_lds(
        (const __attribute__((address_space(1))) unsigned int*)g,
        (__attribute__((address_space(3))) unsigned int*)l, 16, 0, 0);
}

// ---- fused fp32->bf16 convert + per-pixel channel sums (16 lanes = 1 pixel) ----
__global__ __launch_bounds__(256) void cvt_pix(
    const float* __restrict__ in1, const float* __restrict__ in2,
    u32* __restrict__ o1, u32* __restrict__ o2,
    float* __restrict__ pS1, float* __restrict__ pQ1,
    float* __restrict__ pS2, float* __restrict__ pQ2)
{
    int i = blockIdx.x * 256 + threadIdx.x;   // [0, NELEM/4)
    f32x4 a = *(const f32x4*)(in1 + (size_t)i*4);
    f32x4 c = *(const f32x4*)(in2 + (size_t)i*4);
    u32x2 pa = { pack2_bf16(a.x, a.y), pack2_bf16(a.z, a.w) };
    u32x2 pc = { pack2_bf16(c.x, c.y), pack2_bf16(c.z, c.w) };
    ((u32x2*)o1)[i] = pa;
    ((u32x2*)o2)[i] = pc;
    float s1 = a.x + a.y + a.z + a.w;
    float q1 = a.x*a.x + a.y*a.y + a.z*a.z + a.w*a.w;
    float s2 = c.x + c.y + c.z + c.w;
    float q2 = c.x*c.x + c.y*c.y + c.z*c.z + c.w*c.w;
#pragma unroll
    for (int off = 1; off < 16; off <<= 1) {
        s1 += __shfl_xor(s1, off); q1 += __shfl_xor(q1, off);
        s2 += __shfl_xor(s2, off); q2 += __shfl_xor(q2, off);
    }
    if ((threadIdx.x & 15) == 0) {
        int p = i >> 4;
        pS1[p] = s1; pQ1[p] = q1; pS2[p] = s2; pQ2[p] = q2;
    }
}

// ---- per-patch mean / invstd from pixel partial sums ----
__global__ __launch_bounds__(256) void pstats(
    const float* __restrict__ pS1, const float* __restrict__ pQ1,
    const float* __restrict__ pS2, const float* __restrict__ pQ2,
    float* __restrict__ meanArr, float* __restrict__ invstdArr)
{
    int gid = blockIdx.x * 256 + threadIdx.x;
    if (gid >= NP2 + NP1) return;
    const float *pS, *pQ; int b, y, x;
    if (gid < NP2) {
        b = gid / P2N; int p = gid % P2N;
        y = p / OUTC; x = p % OUTC;
        pS = pS2; pQ = pQ2;
    } else {
        int g = gid - NP2;
        b = g / P1N; int p = g % P1N;
        y = (p / P1C) * 2; x = (p % P1C) * 2;
        pS = pS1; pQ = pQ1;
    }
    int base = (b*HH + y)*WW + x;
    float s = 0.f, q = 0.f;
#pragma unroll
    for (int dy = 0; dy < 5; ++dy)
#pragma unroll
        for (int dx = 0; dx < 5; ++dx) {
            int pp = base + dy*WW + dx;
            s += pS[pp]; q += pQ[pp];
        }
    float m = s * (1.f / KF);
    meanArr[gid] = m;
    invstdArr[gid] = rsqrtf(q * (1.f / KF) - m * m);
}

// ---- fallback exact-fp32 stats (only used if ws too small) ----
__global__ __launch_bounds__(256) void stats_kernel(
    const float* __restrict__ in1, const float* __restrict__ in2,
    float* __restrict__ meanArr, float* __restrict__ invstdArr)
{
    int gid = blockIdx.x * 4 + (threadIdx.x >> 6);
    int lane = threadIdx.x & 63;
    const float* src; int b, y, x;
    if (gid < NP2) {
        b = gid / P2N; int p = gid % P2N;
        y = p / OUTC; x = p % OUTC;
        src = in2;
    } else {
        int g = gid - NP2;
        b = g / P1N; int p = g % P1N;
        y = (p / P1C) * 2; x = (p % P1C) * 2;
        src = in1;
    }
    const float* base = src + (((b*HH + y)*WW + x)*CC) + lane;
    float s = 0.f, s2 = 0.f;
#pragma unroll
    for (int i = 0; i < 25; ++i) {
        int dy = i / 5, dx = i % 5;
        float v = base[(dy*WW + dx)*CC];
        s += v; s2 += v * v;
    }
#pragma unroll
    for (int off = 32; off; off >>= 1) {
        s  += __shfl_xor(s, off);
        s2 += __shfl_xor(s2, off);
    }
    if (lane == 0) {
        float m = s * (1.f / KF);
        float var = s2 * (1.f / KF) - m * m;
        meanArr[gid] = m;
        invstdArr[gid] = rsqrtf(var);
    }
}

// ====== pixel-shared MFMA correlation: stage image rows ONCE, barrier-free K-loop ======
// Block 256x128 (patches), 8 waves (4m x 2n) of 64x64. LDS holds the block's
// underlying PIXEL rows: A 14 rows (56K) + B 23 rows (92K) = 148 KB, staged once
// via glds16 (linear dest, x-swizzled source col: A key x&7, B key (x>>1)&7).
// HARDENED barrier: explicit vmcnt(0) drain (glds has no reg dest -> dataflow
// waitcnt insertion cannot order it; force the drain) + __syncthreads.
// K-loop (25 (dy,dx) chunks): pure ds_read_b128 + MFMA, no barriers, no staging.
__global__ __launch_bounds__(512) void corr_pix(
    const short* __restrict__ a2, const short* __restrict__ b1i,
    const float* __restrict__ meanArr, const float* __restrict__ invstdArr,
    float* __restrict__ out)
{
    __shared__ __align__(16) short lds[(ABYTES + BBYTES)/2];   // 148 KB
    char* Lc = (char*)lds;

    const int b  = blockIdx.x;            // batch fastest -> XCD affinity
    const int n0 = blockIdx.y * BN;
    const int m0 = blockIdx.z * BM;
    const int t  = threadIdx.x;
    const int lane = t & 63, wid = t >> 6;
    const int wm = wid >> 1, wn = wid & 1;       // 4x2 waves -> 64x64 tiles
    const int fr = lane & 15, fh = lane >> 4;

    const int ybA = m0 / OUTC;            // first y2 of this M-block
    const int ybB = 2 * (n0 / P1C);       // first y1 of this N-block
    const int wbase = wid * 1024;         // wave's linear 1KB slot per round

    // ---- stage A pixel rows: 14 rows x 32px x 64ch, 7 rounds x 8KB ----
#pragma unroll
    for (int r = 0; r < 7; ++r) {
        int flat = r*512 + t;             // unit = 16B: [prow][px][c16]
        int prow = flat >> 8;
        int px   = (flat >> 3) & 31;
        int c16  = flat & 7;
        int y = ybA + prow; if (y > HH-1) y = HH-1;
        glds16(a2 + ((b*HH + y)*WW + px)*CC + ((c16 ^ (px & 7)) * 8),
               Lc + r*8192 + wbase);
    }
    // ---- stage B pixel rows: 23 rows, 11.5 rounds (last round waves 0-3 only) ----
#pragma unroll
    for (int r = 0; r < 12; ++r) {
        if (r < 11 || wid < 4) {
            int flat = r*512 + t;
            int prow = flat >> 8;
            int px   = (flat >> 3) & 31;
            int c16  = flat & 7;
            int y = ybB + prow; if (y > HH-1) y = HH-1;
            glds16(b1i + ((b*HH + y)*WW + px)*CC + ((c16 ^ ((px >> 1) & 7)) * 8),
                   Lc + ABYTES + r*8192 + wbase);
        }
    }

    // ---- per-lane patch pixel bases ----
    int pA[4], pB[4];
#pragma unroll
    for (int i = 0; i < 4; ++i) {
        int ma = m0 + wm*64 + i*16 + fr; if (ma > P2N-1) ma = P2N-1;
        pA[i] = (ma/OUTC - ybA)*32 + ma%OUTC;
    }
#pragma unroll
    for (int j = 0; j < 4; ++j) {
        int n = n0 + wn*64 + j*16 + fr; if (n > P1N-1) n = P1N-1;
        pB[j] = (2*(n/P1C) - ybB)*32 + 2*(n%P1C);
    }

    f32x4 acc[4][4];
#pragma unroll
    for (int i = 0; i < 4; ++i)
#pragma unroll
        for (int j = 0; j < 4; ++j) acc[i][j] = (f32x4){0.f,0.f,0.f,0.f};

    // ---- HARDENED staging barrier: force glds drain in every wave ----
    __builtin_amdgcn_sched_barrier(0);
    asm volatile("s_waitcnt vmcnt(0) lgkmcnt(0)" ::: "memory");
    __syncthreads();
    __builtin_amdgcn_sched_barrier(0);

    const int colb = fh * 16;
#pragma unroll
    for (int kk = 0; kk < 25; ++kk) {
        const int dy = kk / 5, dx = kk % 5;
        const int po = dy*32 + dx;
        s16x8 af[2][4], bfr[2][4];
#pragma unroll
        for (int i = 0; i < 4; ++i) {
            int p = pA[i] + po;
            int sw = (p & 7) << 4;
            const char* base = Lc + p*128;
            af[0][i] = *(const s16x8*)(base + (colb ^ sw));
            af[1][i] = *(const s16x8*)(base + ((64 + colb) ^ sw));
        }
#pragma unroll
        for (int j = 0; j < 4; ++j) {
            int p = pB[j] + po;
            int sw = ((p >> 1) & 7) << 4;
            const char* base = Lc + ABYTES + p*128;
            bfr[0][j] = *(const s16x8*)(base + (colb ^ sw));
            bfr[1][j] = *(const s16x8*)(base + ((64 + colb) ^ sw));
        }
#pragma unroll
        for (int s = 0; s < 2; ++s)
#pragma unroll
            for (int i = 0; i < 4; ++i)
#pragma unroll
                for (int j = 0; j < 4; ++j)
                    acc[i][j] = __builtin_amdgcn_mfma_f32_16x16x32_bf16(af[s][i], bfr[s][j], acc[i][j], 0, 0, 0);
    }

    // ---- epilogue: (dot - K*m2*m1) * is2 * is1 ----
    float m1v[4], is1v[4];
#pragma unroll
    for (int j = 0; j < 4; ++j) {
        int n = n0 + wn*64 + j*16 + fr;
        int nc = n > P1N-1 ? P1N-1 : n;
        m1v[j]  = meanArr[NP2 + b*P1N + nc];
        is1v[j] = invstdArr[NP2 + b*P1N + nc];
    }
#pragma unroll
    for (int i = 0; i < 4; ++i) {
#pragma unroll
        for (int r = 0; r < 4; ++r) {
            int m = m0 + wm*64 + i*16 + fh*4 + r;
            if (m >= P2N) continue;
            float m2  = meanArr[b*P2N + m];
            float is2 = invstdArr[b*P2N + m];
            size_t obase = ((size_t)b*P2N + m) * P1N;
#pragma unroll
            for (int j = 0; j < 4; ++j) {
                int n = n0 + wn*64 + j*16 + fr;
                if (n >= P1N) continue;
                out[obase + n] = (acc[i][j][r] - (float)KF * m2 * m1v[j]) * is2 * is1v[j];
            }
        }
    }
}

// ---- fallback fp32 corr (128x128 tile; used only if ws too small) ----
__global__ __launch_bounds__(256) void corr_fp32(
    const float* __restrict__ aF, const float* __restrict__ bF,
    const float* __restrict__ meanArr, const float* __restrict__ invstdArr,
    float* __restrict__ out)
{
    __shared__ short As[2][128*64];
    __shared__ short Bs[2][128*64];
    const int b  = blockIdx.z;
    const int m0 = blockIdx.y * 128;
    const int n0 = blockIdx.x * 128;
    const int t  = threadIdx.x;
    const int lane = t & 63;
    const int wid  = t >> 6;
    const int wm = wid >> 1, wn = wid & 1;
    const int fr = lane & 15, fh = lane >> 4;
    const int rsub = t >> 3, c16 = t & 7;
    const int colElem = c16 * 8;
    const int swz = (rsub & 7) << 4;
    const int wByte = rsub*128 + c16*16;

    int aOff[4], bOff[4];
#pragma unroll
    for (int q = 0; q < 4; ++q) {
        int ma = m0 + rsub + 32*q; if (ma > P2N-1) ma = P2N-1;
        int y = ma / OUTC, x = ma % OUTC;
        aOff[q] = ((b*HH + y)*WW + x)*CC;
        int nb = n0 + rsub + 32*q; if (nb > P1N-1) nb = P1N-1;
        int yy = (nb / P1C)*2, xx = (nb % P1C)*2;
        bOff[q] = ((b*HH + yy)*WW + xx)*CC;
    }
    f32x4 acc[4][4];
#pragma unroll
    for (int i = 0; i < 4; ++i)
#pragma unroll
        for (int j = 0; j < 4; ++j) acc[i][j] = (f32x4){0.f,0.f,0.f,0.f};

    f32x4 avF[4][2], bvF[4][2];
#pragma unroll
    for (int q = 0; q < 4; ++q) {
        avF[q][0] = *(const f32x4*)(aF + aOff[q] + colElem);
        avF[q][1] = *(const f32x4*)(aF + aOff[q] + colElem + 4);
        bvF[q][0] = *(const f32x4*)(bF + bOff[q] + colElem);
        bvF[q][1] = *(const f32x4*)(bF + bOff[q] + colElem + 4);
    }
    {
        char* AsB = (char*)As[0]; char* BsB = (char*)Bs[0];
#pragma unroll
        for (int q = 0; q < 4; ++q) {
            u32x4 va = { pack2_bf16(avF[q][0].x, avF[q][0].y), pack2_bf16(avF[q][0].z, avF[q][0].w),
                         pack2_bf16(avF[q][1].x, avF[q][1].y), pack2_bf16(avF[q][1].z, avF[q][1].w) };
            u32x4 vb = { pack2_bf16(bvF[q][0].x, bvF[q][0].y), pack2_bf16(bvF[q][0].z, bvF[q][0].w),
                         pack2_bf16(bvF[q][1].x, bvF[q][1].y), pack2_bf16(bvF[q][1].z, bvF[q][1].w) };
            *(u32x4*)(AsB + ((wByte + q*4096) ^ swz)) = va;
            *(u32x4*)(BsB + ((wByte + q*4096) ^ swz)) = vb;
        }
    }
    for (int kk = 0; kk < 25; ++kk) {
        __syncthreads();
        if (kk < 24) {
            int kn = kk + 1;
            int goff = ((kn/5)*WW + (kn%5))*CC + colElem;
#pragma unroll
            for (int q = 0; q < 4; ++q) {
                avF[q][0] = *(const f32x4*)(aF + aOff[q] + goff);
                avF[q][1] = *(const f32x4*)(aF + aOff[q] + goff + 4);
                bvF[q][0] = *(const f32x4*)(bF + bOff[q] + goff);
                bvF[q][1] = *(const f32x4*)(bF + bOff[q] + goff + 4);
            }
        }
        {
            const char* AsB = (const char*)As[kk & 1];
            const char* BsB = (const char*)Bs[kk & 1];
#pragma unroll
            for (int step = 0; step < 2; ++step) {
                s16x8 af[4], bfr[4];
#pragma unroll
                for (int i = 0; i < 4; ++i) {
                    int row = wm*64 + i*16 + fr;
                    af[i] = *(const s16x8*)(AsB + ((row*128 + step*64 + fh*16) ^ ((fr & 7) << 4)));
                }
#pragma unroll
                for (int j = 0; j < 4; ++j) {
                    int row = wn*64 + j*16 + fr;
                    bfr[j] = *(const s16x8*)(BsB + ((row*128 + step*64 + fh*16) ^ ((fr & 7) << 4)));
                }
#pragma unroll
                for (int i = 0; i < 4; ++i)
#pragma unroll
                    for (int j = 0; j < 4; ++j)
                        acc[i][j] = __builtin_amdgcn_mfma_f32_16x16x32_bf16(af[i], bfr[j], acc[i][j], 0, 0, 0);
            }
        }
        if (kk < 24) {
            char* AsB = (char*)As[(kk + 1) & 1];
            char* BsB = (char*)Bs[(kk + 1) & 1];
#pragma unroll
            for (int q = 0; q < 4; ++q) {
                u32x4 va = { pack2_bf16(avF[q][0].x, avF[q][0].y), pack2_bf16(avF[q][0].z, avF[q][0].w),
                             pack2_bf16(avF[q][1].x, avF[q][1].y), pack2_bf16(avF[q][1].z, avF[q][1].w) };
                u32x4 vb = { pack2_bf16(bvF[q][0].x, bvF[q][0].y), pack2_bf16(bvF[q][0].z, bvF[q][0].w),
                             pack2_bf16(bvF[q][1].x, bvF[q][1].y), pack2_bf16(bvF[q][1].z, bvF[q][1].w) };
                *(u32x4*)(AsB + ((wByte + q*4096) ^ swz)) = va;
                *(u32x4*)(BsB + ((wByte + q*4096) ^ swz)) = vb;
            }
        }
    }
    float m1v[4], is1v[4];
#pragma unroll
    for (int j = 0; j < 4; ++j) {
        int n = n0 + wn*64 + j*16 + fr;
        int nc = n > P1N-1 ? P1N-1 : n;
        m1v[j]  = meanArr[NP2 + b*P1N + nc];
        is1v[j] = invstdArr[NP2 + b*P1N + nc];
    }
#pragma unroll
    for (int i = 0; i < 4; ++i) {
#pragma unroll
        for (int r = 0; r < 4; ++r) {
            int m = m0 + wm*64 + i*16 + fh*4 + r;
            if (m >= P2N) continue;
            float m2  = meanArr[b*P2N + m];
            float is2 = invstdArr[b*P2N + m];
            size_t obase = ((size_t)b*P2N + m) * P1N;
#pragma unroll
            for (int j = 0; j < 4; ++j) {
                int n = n0 + wn*64 + j*16 + fr;
                if (n >= P1N) continue;
                out[obase + n] = (acc[i][j][r] - (float)KF * m2 * m1v[j]) * is2 * is1v[j];
            }
        }
    }
}

extern "C" void kernel_launch(void* const* d_in, const int* in_sizes, int n_in,
                              void* d_out, int out_size, void* d_ws, size_t ws_size,
                              hipStream_t stream) {
    const float* in1 = (const float*)d_in[0];   // strided patches -> N side
    const float* in2 = (const float*)d_in[1];   // dense patches   -> M side
    float* out = (float*)d_out;

    float* meanArr   = (float*)d_ws;
    float* invstdArr = meanArr + (NP2 + NP1);
    float* pS1 = invstdArr + (NP2 + NP1);
    float* pQ1 = pS1 + NPIX;
    float* pS2 = pQ1 + NPIX;
    float* pQ2 = pS2 + NPIX;
    short* b1 = (short*)(pQ2 + NPIX);           // bf16 input_1
    short* b2 = b1 + NELEM;                     // bf16 input_2
    size_t need = (size_t)((char*)(b2 + NELEM) - (char*)d_ws);
    bool useBf16 = (ws_size >= need);

    if (useBf16) {
        // grid: batch FASTEST -> XCD L2 affinity; 8 x 4 x 7 = 224 blocks (1 round)
        dim3 grid(NB, (P1N + BN - 1) / BN, (P2N + BM - 1) / BM);
        cvt_pix<<<NELEM/4/256, 256, 0, stream>>>(in1, in2, (u32*)b1, (u32*)b2,
                                                 pS1, pQ1, pS2, pQ2);
        pstats<<<(NP2 + NP1 + 255)/256, 256, 0, stream>>>(pS1, pQ1, pS2, pQ2,
                                                          meanArr, invstdArr);
        corr_pix<<<grid, 512, 0, stream>>>(b2, b1, meanArr, invstdArr, out);
    } else {
        dim3 gridF((P1N + 127) / 128, (P2N + 127) / 128, NB);
        stats_kernel<<<(NP2 + NP1) / 4, 256, 0, stream>>>(in1, in2, meanArr, invstdArr);
        corr_fp32<<<gridF, 256, 0, stream>>>(in2, in1, meanArr, invstdArr, out);
    }
}

// Round 15
// 43.063 us; speedup vs baseline: 1.0123x; 1.0123x over previous
//
#include <hip/hip_runtime.h>

typedef float f32x4 __attribute__((ext_vector_type(4)));
typedef short s16x8 __attribute__((ext_vector_type(8)));
typedef unsigned int u32;
typedef u32 u32x2 __attribute__((ext_vector_type(2)));
typedef u32 u32x4 __attribute__((ext_vector_type(4)));

#define NB 8
#define HH 64
#define WW 32
#define CC 64
#define P2N 1680   // dense patches (input_2) = M
#define P1N 420    // strided patches (input_1) = N
#define OUTC 28
#define P1C 14
#define KF 1600
#define NP2 (NB*P2N)
#define NP1 (NB*P1N)
#define NELEM (NB*HH*WW*CC)   // 1048576
#define NPIX (NB*HH*WW)       // 16384

#define BM 256
#define BN 128
#define AROWS 14              // max y2-span(10) + PATCH-1
#define BROWS 23              // max y1-span(19) + PATCH-1
#define ABYTES (AROWS*32*128) // 57344
#define BBYTES (BROWS*32*128) // 94208

__device__ __forceinline__ u32 pack2_bf16(float x, float y) {
    u32 ux = __builtin_bit_cast(u32, x);
    u32 uy = __builtin_bit_cast(u32, y);
    ux = (ux + 0x7FFFu + ((ux >> 16) & 1u)) >> 16;
    uy = (uy + 0x7FFFu + ((uy >> 16) & 1u)) & 0xFFFF0000u;
    return (ux & 0xFFFFu) | uy;
}

__device__ __forceinline__ void glds16(const void* g, void* l) {
    __builtin_amdgcn_global_load_lds(
        (const __attribute__((address_space(1))) unsigned int*)g,
        (__attribute__((address_space(3))) unsigned int*)l, 16, 0, 0);
}

// ---- fused fp32->bf16 convert + per-pixel channel sums (16 lanes = 1 pixel) ----
__global__ __launch_bounds__(256) void cvt_pix(
    const float* __restrict__ in1, const float* __restrict__ in2,
    u32* __restrict__ o1, u32* __restrict__ o2,
    float* __restrict__ pS1, float* __restrict__ pQ1,
    float* __restrict__ pS2, float* __restrict__ pQ2)
{
    int i = blockIdx.x * 256 + threadIdx.x;   // [0, NELEM/4)
    f32x4 a = *(const f32x4*)(in1 + (size_t)i*4);
    f32x4 c = *(const f32x4*)(in2 + (size_t)i*4);
    u32x2 pa = { pack2_bf16(a.x, a.y), pack2_bf16(a.z, a.w) };
    u32x2 pc = { pack2_bf16(c.x, c.y), pack2_bf16(c.z, c.w) };
    ((u32x2*)o1)[i] = pa;
    ((u32x2*)o2)[i] = pc;
    float s1 = a.x + a.y + a.z + a.w;
    float q1 = a.x*a.x + a.y*a.y + a.z*a.z + a.w*a.w;
    float s2 = c.x + c.y + c.z + c.w;
    float q2 = c.x*c.x + c.y*c.y + c.z*c.z + c.w*c.w;
#pragma unroll
    for (int off = 1; off < 16; off <<= 1) {
        s1 += __shfl_xor(s1, off); q1 += __shfl_xor(q1, off);
        s2 += __shfl_xor(s2, off); q2 += __shfl_xor(q2, off);
    }
    if ((threadIdx.x & 15) == 0) {
        int p = i >> 4;
        pS1[p] = s1; pQ1[p] = q1; pS2[p] = s2; pQ2[p] = q2;
    }
}

// ---- per-patch mean / invstd from pixel partial sums ----
__global__ __launch_bounds__(256) void pstats(
    const float* __restrict__ pS1, const float* __restrict__ pQ1,
    const float* __restrict__ pS2, const float* __restrict__ pQ2,
    float* __restrict__ meanArr, float* __restrict__ invstdArr)
{
    int gid = blockIdx.x * 256 + threadIdx.x;
    if (gid >= NP2 + NP1) return;
    const float *pS, *pQ; int b, y, x;
    if (gid < NP2) {
        b = gid / P2N; int p = gid % P2N;
        y = p / OUTC; x = p % OUTC;
        pS = pS2; pQ = pQ2;
    } else {
        int g = gid - NP2;
        b = g / P1N; int p = g % P1N;
        y = (p / P1C) * 2; x = (p % P1C) * 2;
        pS = pS1; pQ = pQ1;
    }
    int base = (b*HH + y)*WW + x;
    float s = 0.f, q = 0.f;
#pragma unroll
    for (int dy = 0; dy < 5; ++dy)
#pragma unroll
        for (int dx = 0; dx < 5; ++dx) {
            int pp = base + dy*WW + dx;
            s += pS[pp]; q += pQ[pp];
        }
    float m = s * (1.f / KF);
    meanArr[gid] = m;
    invstdArr[gid] = rsqrtf(q * (1.f / KF) - m * m);
}

// ---- fallback exact-fp32 stats (only used if ws too small) ----
__global__ __launch_bounds__(256) void stats_kernel(
    const float* __restrict__ in1, const float* __restrict__ in2,
    float* __restrict__ meanArr, float* __restrict__ invstdArr)
{
    int gid = blockIdx.x * 4 + (threadIdx.x >> 6);
    int lane = threadIdx.x & 63;
    const float* src; int b, y, x;
    if (gid < NP2) {
        b = gid / P2N; int p = gid % P2N;
        y = p / OUTC; x = p % OUTC;
        src = in2;
    } else {
        int g = gid - NP2;
        b = g / P1N; int p = g % P1N;
        y = (p / P1C) * 2; x = (p % P1C) * 2;
        src = in1;
    }
    const float* base = src + (((b*HH + y)*WW + x)*CC) + lane;
    float s = 0.f, s2 = 0.f;
#pragma unroll
    for (int i = 0; i < 25; ++i) {
        int dy = i / 5, dx = i % 5;
        float v = base[(dy*WW + dx)*CC];
        s += v; s2 += v * v;
    }
#pragma unroll
    for (int off = 32; off; off >>= 1) {
        s  += __shfl_xor(s, off);
        s2 += __shfl_xor(s2, off);
    }
    if (lane == 0) {
        float m = s * (1.f / KF);
        float var = s2 * (1.f / KF) - m * m;
        meanArr[gid] = m;
        invstdArr[gid] = rsqrtf(var);
    }
}

// ====== pixel-shared MFMA correlation + register-double-buffered fragments ======
// Block 256x128 (patches), 8 waves (4m x 2n) of 64x64. LDS = pixel rows staged
// once (A 56K + B 92K = 148 KB, glds16, x-swizzled source). Hardened barrier.
// K-loop: fragments for chunk kk+1 ds_read-issued BEFORE chunk kk's MFMAs
// (named X/Y register sets, no dynamic indexing), so LDS latency hides under
// the MFMA cluster. __launch_bounds__(512,1) unlocks ~256 VGPRs (1 block/CU
// anyway due to LDS).
__global__ __launch_bounds__(512, 1) void corr_pix(
    const short* __restrict__ a2, const short* __restrict__ b1i,
    const float* __restrict__ meanArr, const float* __restrict__ invstdArr,
    float* __restrict__ out)
{
    __shared__ __align__(16) short lds[(ABYTES + BBYTES)/2];   // 148 KB
    char* Lc = (char*)lds;

    const int b  = blockIdx.x;            // batch fastest -> XCD affinity
    const int n0 = blockIdx.y * BN;
    const int m0 = blockIdx.z * BM;
    const int t  = threadIdx.x;
    const int lane = t & 63, wid = t >> 6;
    const int wm = wid >> 1, wn = wid & 1;       // 4x2 waves -> 64x64 tiles
    const int fr = lane & 15, fh = lane >> 4;

    const int ybA = m0 / OUTC;            // first y2 of this M-block
    const int ybB = 2 * (n0 / P1C);       // first y1 of this N-block
    const int wbase = wid * 1024;         // wave's linear 1KB slot per round

    // ---- stage A pixel rows: 14 rows x 32px x 64ch, 7 rounds x 8KB ----
#pragma unroll
    for (int r = 0; r < 7; ++r) {
        int flat = r*512 + t;             // unit = 16B: [prow][px][c16]
        int prow = flat >> 8;
        int px   = (flat >> 3) & 31;
        int c16  = flat & 7;
        int y = ybA + prow; if (y > HH-1) y = HH-1;
        glds16(a2 + ((b*HH + y)*WW + px)*CC + ((c16 ^ (px & 7)) * 8),
               Lc + r*8192 + wbase);
    }
    // ---- stage B pixel rows: 23 rows, 11.5 rounds (last round waves 0-3 only) ----
#pragma unroll
    for (int r = 0; r < 12; ++r) {
        if (r < 11 || wid < 4) {
            int flat = r*512 + t;
            int prow = flat >> 8;
            int px   = (flat >> 3) & 31;
            int c16  = flat & 7;
            int y = ybB + prow; if (y > HH-1) y = HH-1;
            glds16(b1i + ((b*HH + y)*WW + px)*CC + ((c16 ^ ((px >> 1) & 7)) * 8),
                   Lc + ABYTES + r*8192 + wbase);
        }
    }

    // ---- per-lane patch pixel bases ----
    int pA[4], pB[4];
#pragma unroll
    for (int i = 0; i < 4; ++i) {
        int ma = m0 + wm*64 + i*16 + fr; if (ma > P2N-1) ma = P2N-1;
        pA[i] = (ma/OUTC - ybA)*32 + ma%OUTC;
    }
#pragma unroll
    for (int j = 0; j < 4; ++j) {
        int n = n0 + wn*64 + j*16 + fr; if (n > P1N-1) n = P1N-1;
        pB[j] = (2*(n/P1C) - ybB)*32 + 2*(n%P1C);
    }

    f32x4 acc[4][4];
#pragma unroll
    for (int i = 0; i < 4; ++i)
#pragma unroll
        for (int j = 0; j < 4; ++j) acc[i][j] = (f32x4){0.f,0.f,0.f,0.f};

    // ---- HARDENED staging barrier: force glds drain in every wave ----
    __builtin_amdgcn_sched_barrier(0);
    asm volatile("s_waitcnt vmcnt(0) lgkmcnt(0)" ::: "memory");
    __syncthreads();
    __builtin_amdgcn_sched_barrier(0);

    const int colb = fh * 16;

    s16x8 aX[2][4], bX[2][4], aY[2][4], bY[2][4];   // two named fragment sets

#define LOADSET(AF, BF, PO) { \
    _Pragma("unroll") for (int i = 0; i < 4; ++i) { \
        int p = pA[i] + (PO); \
        int sw = (p & 7) << 4; \
        const char* base = Lc + p*128; \
        AF[0][i] = *(const s16x8*)(base + (colb ^ sw)); \
        AF[1][i] = *(const s16x8*)(base + ((64 + colb) ^ sw)); } \
    _Pragma("unroll") for (int j = 0; j < 4; ++j) { \
        int p = pB[j] + (PO); \
        int sw = ((p >> 1) & 7) << 4; \
        const char* base = Lc + ABYTES + p*128; \
        BF[0][j] = *(const s16x8*)(base + (colb ^ sw)); \
        BF[1][j] = *(const s16x8*)(base + ((64 + colb) ^ sw)); } }

#define MFMASET(AF, BF) { \
    _Pragma("unroll") for (int s = 0; s < 2; ++s) \
        _Pragma("unroll") for (int i = 0; i < 4; ++i) \
            _Pragma("unroll") for (int j = 0; j < 4; ++j) \
                acc[i][j] = __builtin_amdgcn_mfma_f32_16x16x32_bf16(AF[s][i], BF[s][j], acc[i][j], 0, 0, 0); }

#define POOF(kk) (((kk)/5)*32 + ((kk)%5))

    LOADSET(aX, bX, POOF(0));
#pragma unroll
    for (int kk = 0; kk < 25; ++kk) {
        if ((kk & 1) == 0) {
            if (kk < 24) LOADSET(aY, bY, POOF(kk + 1));
            MFMASET(aX, bX);
        } else {
            if (kk < 24) LOADSET(aX, bX, POOF(kk + 1));
            MFMASET(aY, bY);
        }
    }
#undef LOADSET
#undef MFMASET
#undef POOF

    // ---- epilogue: (dot - K*m2*m1) * is2 * is1 ----
    float m1v[4], is1v[4];
#pragma unroll
    for (int j = 0; j < 4; ++j) {
        int n = n0 + wn*64 + j*16 + fr;
        int nc = n > P1N-1 ? P1N-1 : n;
        m1v[j]  = meanArr[NP2 + b*P1N + nc];
        is1v[j] = invstdArr[NP2 + b*P1N + nc];
    }
#pragma unroll
    for (int i = 0; i < 4; ++i) {
#pragma unroll
        for (int r = 0; r < 4; ++r) {
            int m = m0 + wm*64 + i*16 + fh*4 + r;
            if (m >= P2N) continue;
            float m2  = meanArr[b*P2N + m];
            float is2 = invstdArr[b*P2N + m];
            size_t obase = ((size_t)b*P2N + m) * P1N;
#pragma unroll
            for (int j = 0; j < 4; ++j) {
                int n = n0 + wn*64 + j*16 + fr;
                if (n >= P1N) continue;
                out[obase + n] = (acc[i][j][r] - (float)KF * m2 * m1v[j]) * is2 * is1v[j];
            }
        }
    }
}

// ---- fallback fp32 corr (128x128 tile; used only if ws too small) ----
__global__ __launch_bounds__(256) void corr_fp32(
    const float* __restrict__ aF, const float* __restrict__ bF,
    const float* __restrict__ meanArr, const float* __restrict__ invstdArr,
    float* __restrict__ out)
{
    __shared__ short As[2][128*64];
    __shared__ short Bs[2][128*64];
    const int b  = blockIdx.z;
    const int m0 = blockIdx.y * 128;
    const int n0 = blockIdx.x * 128;
    const int t  = threadIdx.x;
    const int lane = t & 63;
    const int wid  = t >> 6;
    const int wm = wid >> 1, wn = wid & 1;
    const int fr = lane & 15, fh = lane >> 4;
    const int rsub = t >> 3, c16 = t & 7;
    const int colElem = c16 * 8;
    const int swz = (rsub & 7) << 4;
    const int wByte = rsub*128 + c16*16;

    int aOff[4], bOff[4];
#pragma unroll
    for (int q = 0; q < 4; ++q) {
        int ma = m0 + rsub + 32*q; if (ma > P2N-1) ma = P2N-1;
        int y = ma / OUTC, x = ma % OUTC;
        aOff[q] = ((b*HH + y)*WW + x)*CC;
        int nb = n0 + rsub + 32*q; if (nb > P1N-1) nb = P1N-1;
        int yy = (nb / P1C)*2, xx = (nb % P1C)*2;
        bOff[q] = ((b*HH + yy)*WW + xx)*CC;
    }
    f32x4 acc[4][4];
#pragma unroll
    for (int i = 0; i < 4; ++i)
#pragma unroll
        for (int j = 0; j < 4; ++j) acc[i][j] = (f32x4){0.f,0.f,0.f,0.f};

    f32x4 avF[4][2], bvF[4][2];
#pragma unroll
    for (int q = 0; q < 4; ++q) {
        avF[q][0] = *(const f32x4*)(aF + aOff[q] + colElem);
        avF[q][1] = *(const f32x4*)(aF + aOff[q] + colElem + 4);
        bvF[q][0] = *(const f32x4*)(bF + bOff[q] + colElem);
        bvF[q][1] = *(const f32x4*)(bF + bOff[q] + colElem + 4);
    }
    {
        char* AsB = (char*)As[0]; char* BsB = (char*)Bs[0];
#pragma unroll
        for (int q = 0; q < 4; ++q) {
            u32x4 va = { pack2_bf16(avF[q][0].x, avF[q][0].y), pack2_bf16(avF[q][0].z, avF[q][0].w),
                         pack2_bf16(avF[q][1].x, avF[q][1].y), pack2_bf16(avF[q][1].z, avF[q][1].w) };
            u32x4 vb = { pack2_bf16(bvF[q][0].x, bvF[q][0].y), pack2_bf16(bvF[q][0].z, bvF[q][0].w),
                         pack2_bf16(bvF[q][1].x, bvF[q][1].y), pack2_bf16(bvF[q][1].z, bvF[q][1].w) };
            *(u32x4*)(AsB + ((wByte + q*4096) ^ swz)) = va;
            *(u32x4*)(BsB + ((wByte + q*4096) ^ swz)) = vb;
        }
    }
    for (int kk = 0; kk < 25; ++kk) {
        __syncthreads();
        if (kk < 24) {
            int kn = kk + 1;
            int goff = ((kn/5)*WW + (kn%5))*CC + colElem;
#pragma unroll
            for (int q = 0; q < 4; ++q) {
                avF[q][0] = *(const f32x4*)(aF + aOff[q] + goff);
                avF[q][1] = *(const f32x4*)(aF + aOff[q] + goff + 4);
                bvF[q][0] = *(const f32x4*)(bF + bOff[q] + goff);
                bvF[q][1] = *(const f32x4*)(bF + bOff[q] + goff + 4);
            }
        }
        {
            const char* AsB = (const char*)As[kk & 1];
            const char* BsB = (const char*)Bs[kk & 1];
#pragma unroll
            for (int step = 0; step < 2; ++step) {
                s16x8 af[4], bfr[4];
#pragma unroll
                for (int i = 0; i < 4; ++i) {
                    int row = wm*64 + i*16 + fr;
                    af[i] = *(const s16x8*)(AsB + ((row*128 + step*64 + fh*16) ^ ((fr & 7) << 4)));
                }
#pragma unroll
                for (int j = 0; j < 4; ++j) {
                    int row = wn*64 + j*16 + fr;
                    bfr[j] = *(const s16x8*)(BsB + ((row*128 + step*64 + fh*16) ^ ((fr & 7) << 4)));
                }
#pragma unroll
                for (int i = 0; i < 4; ++i)
#pragma unroll
                    for (int j = 0; j < 4; ++j)
                        acc[i][j] = __builtin_amdgcn_mfma_f32_16x16x32_bf16(af[i], bfr[j], acc[i][j], 0, 0, 0);
            }
        }
        if (kk < 24) {
            char* AsB = (char*)As[(kk + 1) & 1];
            char* BsB = (char*)Bs[(kk + 1) & 1];
#pragma unroll
            for (int q = 0; q < 4; ++q) {
                u32x4 va = { pack2_bf16(avF[q][0].x, avF[q][0].y), pack2_bf16(avF[q][0].z, avF[q][0].w),
                             pack2_bf16(avF[q][1].x, avF[q][1].y), pack2_bf16(avF[q][1].z, avF[q][1].w) };
                u32x4 vb = { pack2_bf16(bvF[q][0].x, bvF[q][0].y), pack2_bf16(bvF[q][0].z, bvF[q][0].w),
                             pack2_bf16(bvF[q][1].x, bvF[q][1].y), pack2_bf16(bvF[q][1].z, bvF[q][1].w) };
                *(u32x4*)(AsB + ((wByte + q*4096) ^ swz)) = va;
                *(u32x4*)(BsB + ((wByte + q*4096) ^ swz)) = vb;
            }
        }
    }
    float m1v[4], is1v[4];
#pragma unroll
    for (int j = 0; j < 4; ++j) {
        int n = n0 + wn*64 + j*16 + fr;
        int nc = n > P1N-1 ? P1N-1 : n;
        m1v[j]  = meanArr[NP2 + b*P1N + nc];
        is1v[j] = invstdArr[NP2 + b*P1N + nc];
    }
#pragma unroll
    for (int i = 0; i < 4; ++i) {
#pragma unroll
        for (int r = 0; r < 4; ++r) {
            int m = m0 + wm*64 + i*16 + fh*4 + r;
            if (m >= P2N) continue;
            float m2  = meanArr[b*P2N + m];
            float is2 = invstdArr[b*P2N + m];
            size_t obase = ((size_t)b*P2N + m) * P1N;
#pragma unroll
            for (int j = 0; j < 4; ++j) {
                int n = n0 + wn*64 + j*16 + fr;
                if (n >= P1N) continue;
                out[obase + n] = (acc[i][j][r] - (float)KF * m2 * m1v[j]) * is2 * is1v[j];
            }
        }
    }
}

extern "C" void kernel_launch(void* const* d_in, const int* in_sizes, int n_in,
                              void* d_out, int out_size, void* d_ws, size_t ws_size,
                              hipStream_t stream) {
    const float* in1 = (const float*)d_in[0];   // strided patches -> N side
    const float* in2 = (const float*)d_in[1];   // dense patches   -> M side
    float* out = (float*)d_out;

    float* meanArr   = (float*)d_ws;
    float* invstdArr = meanArr + (NP2 + NP1);
    float* pS1 = invstdArr + (NP2 + NP1);
    float* pQ1 = pS1 + NPIX;
    float* pS2 = pQ1 + NPIX;
    float* pQ2 = pS2 + NPIX;
    short* b1 = (short*)(pQ2 + NPIX);           // bf16 input_1
    short* b2 = b1 + NELEM;                     // bf16 input_2
    size_t need = (size_t)((char*)(b2 + NELEM) - (char*)d_ws);
    bool useBf16 = (ws_size >= need);

    if (useBf16) {
        // grid: batch FASTEST -> XCD L2 affinity; 8 x 4 x 7 = 224 blocks (1 round)
        dim3 grid(NB, (P1N + BN - 1) / BN, (P2N + BM - 1) / BM);
        cvt_pix<<<NELEM/4/256, 256, 0, stream>>>(in1, in2, (u32*)b1, (u32*)b2,
                                                 pS1, pQ1, pS2, pQ2);
        pstats<<<(NP2 + NP1 + 255)/256, 256, 0, stream>>>(pS1, pQ1, pS2, pQ2,
                                                          meanArr, invstdArr);
        corr_pix<<<grid, 512, 0, stream>>>(b2, b1, meanArr, invstdArr, out);
    } else {
        dim3 gridF((P1N + 127) / 128, (P2N + 127) / 128, NB);
        stats_kernel<<<(NP2 + NP1) / 4, 256, 0, stream>>>(in1, in2, meanArr, invstdArr);
        corr_fp32<<<gridF, 256, 0, stream>>>(in2, in1, meanArr, invstdArr, out);
    }
}

// Round 16
// 41.314 us; speedup vs baseline: 1.0552x; 1.0423x over previous
//
#include <hip/hip_runtime.h>

typedef float f32x4 __attribute__((ext_vector_type(4)));
typedef short s16x8 __attribute__((ext_vector_type(8)));
typedef unsigned int u32;
typedef u32 u32x2 __attribute__((ext_vector_type(2)));
typedef u32 u32x4 __attribute__((ext_vector_type(4)));

#define NB 8
#define HH 64
#define WW 32
#define CC 64
#define P2N 1680   // dense patches (input_2) = M
#define P1N 420    // strided patches (input_1) = N
#define OUTC 28
#define P1C 14
#define KF 1600
#define NP2 (NB*P2N)
#define NP1 (NB*P1N)
#define NELEM (NB*HH*WW*CC)   // 1048576
#define NPIX (NB*HH*WW)       // 16384

#define BM 128
#define BN 128    // 64 KB LDS dbuf -> 2 blocks/CU; wave tile 64x64 (min LDS/output)

__device__ __forceinline__ u32 pack2_bf16(float x, float y) {
    u32 ux = __builtin_bit_cast(u32, x);
    u32 uy = __builtin_bit_cast(u32, y);
    ux = (ux + 0x7FFFu + ((ux >> 16) & 1u)) >> 16;
    uy = (uy + 0x7FFFu + ((uy >> 16) & 1u)) & 0xFFFF0000u;
    return (ux & 0xFFFFu) | uy;
}

__device__ __forceinline__ void glds16(const void* g, void* l) {
    __builtin_amdgcn_global_load_lds(
        (const __attribute__((address_space(1))) unsigned int*)g,
        (__attribute__((address_space(3))) unsigned int*)l, 16, 0, 0);
}

// ---- fused fp32->bf16 convert + per-pixel channel sums (16 lanes = 1 pixel) ----
__global__ __launch_bounds__(256) void cvt_pix(
    const float* __restrict__ in1, const float* __restrict__ in2,
    u32* __restrict__ o1, u32* __restrict__ o2,
    float* __restrict__ pS1, float* __restrict__ pQ1,
    float* __restrict__ pS2, float* __restrict__ pQ2)
{
    int i = blockIdx.x * 256 + threadIdx.x;   // [0, NELEM/4)
    f32x4 a = *(const f32x4*)(in1 + (size_t)i*4);
    f32x4 c = *(const f32x4*)(in2 + (size_t)i*4);
    u32x2 pa = { pack2_bf16(a.x, a.y), pack2_bf16(a.z, a.w) };
    u32x2 pc = { pack2_bf16(c.x, c.y), pack2_bf16(c.z, c.w) };
    ((u32x2*)o1)[i] = pa;
    ((u32x2*)o2)[i] = pc;
    float s1 = a.x + a.y + a.z + a.w;
    float q1 = a.x*a.x + a.y*a.y + a.z*a.z + a.w*a.w;
    float s2 = c.x + c.y + c.z + c.w;
    float q2 = c.x*c.x + c.y*c.y + c.z*c.z + c.w*c.w;
#pragma unroll
    for (int off = 1; off < 16; off <<= 1) {
        s1 += __shfl_xor(s1, off); q1 += __shfl_xor(q1, off);
        s2 += __shfl_xor(s2, off); q2 += __shfl_xor(q2, off);
    }
    if ((threadIdx.x & 15) == 0) {
        int p = i >> 4;
        pS1[p] = s1; pQ1[p] = q1; pS2[p] = s2; pQ2[p] = q2;
    }
}

// ---- per-patch mean / invstd from pixel partial sums ----
__global__ __launch_bounds__(256) void pstats(
    const float* __restrict__ pS1, const float* __restrict__ pQ1,
    const float* __restrict__ pS2, const float* __restrict__ pQ2,
    float* __restrict__ meanArr, float* __restrict__ invstdArr)
{
    int gid = blockIdx.x * 256 + threadIdx.x;
    if (gid >= NP2 + NP1) return;
    const float *pS, *pQ; int b, y, x;
    if (gid < NP2) {
        b = gid / P2N; int p = gid % P2N;
        y = p / OUTC; x = p % OUTC;
        pS = pS2; pQ = pQ2;
    } else {
        int g = gid - NP2;
        b = g / P1N; int p = g % P1N;
        y = (p / P1C) * 2; x = (p % P1C) * 2;
        pS = pS1; pQ = pQ1;
    }
    int base = (b*HH + y)*WW + x;
    float s = 0.f, q = 0.f;
#pragma unroll
    for (int dy = 0; dy < 5; ++dy)
#pragma unroll
        for (int dx = 0; dx < 5; ++dx) {
            int pp = base + dy*WW + dx;
            s += pS[pp]; q += pQ[pp];
        }
    float m = s * (1.f / KF);
    meanArr[gid] = m;
    invstdArr[gid] = rsqrtf(q * (1.f / KF) - m * m);
}

// ---- fallback exact-fp32 stats (only used if ws too small) ----
__global__ __launch_bounds__(256) void stats_kernel(
    const float* __restrict__ in1, const float* __restrict__ in2,
    float* __restrict__ meanArr, float* __restrict__ invstdArr)
{
    int gid = blockIdx.x * 4 + (threadIdx.x >> 6);
    int lane = threadIdx.x & 63;
    const float* src; int b, y, x;
    if (gid < NP2) {
        b = gid / P2N; int p = gid % P2N;
        y = p / OUTC; x = p % OUTC;
        src = in2;
    } else {
        int g = gid - NP2;
        b = g / P1N; int p = g % P1N;
        y = (p / P1C) * 2; x = (p % P1C) * 2;
        src = in1;
    }
    const float* base = src + (((b*HH + y)*WW + x)*CC) + lane;
    float s = 0.f, s2 = 0.f;
#pragma unroll
    for (int i = 0; i < 25; ++i) {
        int dy = i / 5, dx = i % 5;
        float v = base[(dy*WW + dx)*CC];
        s += v; s2 += v * v;
    }
#pragma unroll
    for (int off = 32; off; off >>= 1) {
        s  += __shfl_xor(s, off);
        s2 += __shfl_xor(s2, off);
    }
    if (lane == 0) {
        float m = s * (1.f / KF);
        float var = s2 * (1.f / KF) - m * m;
        meanArr[gid] = m;
        invstdArr[gid] = rsqrtf(var);
    }
}

// ====== bf16 MFMA correlation GEMM: 128x128 block, 64x64 wave tiles ======
// 4 waves (2x2) of 64x64 -> minimum LDS bytes per output. Dbuf LDS 64 KB
// (A0|B0|A1|B1 @ 16K), 2 blocks/CU. glds w16 staging (linear LDS dest,
// pre-swizzled global source col), counted vmcnt(8) never draining to 0,
// batch-fastest grid -> XCD L2 affinity.
__global__ __launch_bounds__(256) void corr_mfma_bf16(
    const short* __restrict__ aH, const short* __restrict__ bH,
    const float* __restrict__ meanArr, const float* __restrict__ invstdArr,
    float* __restrict__ out)
{
    __shared__ __align__(16) short lds[2*(BM+BN)*64];   // 64 KB
    char* Lc = (char*)lds;

    const int b  = blockIdx.x;            // batch fastest -> XCD == batch
    const int n0 = blockIdx.y * BN;
    const int m0 = blockIdx.z * BM;
    const int t  = threadIdx.x;
    const int lane = t & 63;
    const int wid  = t >> 6;
    const int wm = wid >> 1, wn = wid & 1;      // 2x2 waves -> 64x64 each
    const int fr = lane & 15, fh = lane >> 4;

    // staging geometry: thread t -> row rsub (+32q), 16B unit c16
    const int rsub = t >> 3;           // 0..31
    const int c16  = t & 7;            // 0..7
    const int csw  = (c16 ^ (rsub & 7)) * 8;   // pre-swizzled source column (elems)

    int aIdxS[4], bIdxS[4];
#pragma unroll
    for (int q = 0; q < 4; ++q) {
        int ma = m0 + rsub + 32*q; if (ma > P2N-1) ma = P2N-1;
        int y = ma / OUTC, x = ma % OUTC;
        aIdxS[q] = ((b*HH + y)*WW + x)*CC + csw;
        int nb = n0 + rsub + 32*q; if (nb > P1N-1) nb = P1N-1;
        int yy = (nb / P1C)*2, xx = (nb % P1C)*2;
        bIdxS[q] = ((b*HH + yy)*WW + xx)*CC + csw;
    }

    // MFMA-side LDS read bases (XOR on read matches source pre-swizzle)
    const int swz = (fr & 7) << 4;
    const int rA0 = (wm*64+fr)*128 + ((fh*16) ^ swz);
    const int rA1 = (wm*64+fr)*128 + ((64 + fh*16) ^ swz);
    const int rB0 = 16384 + (wn*64+fr)*128 + ((fh*16) ^ swz);
    const int rB1 = 16384 + (wn*64+fr)*128 + ((64 + fh*16) ^ swz);

    f32x4 acc[4][4];
#pragma unroll
    for (int i = 0; i < 4; ++i)
#pragma unroll
        for (int j = 0; j < 4; ++j) acc[i][j] = (f32x4){0.f,0.f,0.f,0.f};

    const int wslot = wid * 1024;      // wave's linear 1KB slot inside a q-group

#define GOFF(c) ((((c)/5)*WW + ((c)%5))*CC)
#define STAGE(C, P) { \
    _Pragma("unroll") for (int q = 0; q < 4; ++q) \
        glds16(aH + aIdxS[q] + GOFF(C), Lc + (P)*32768 + q*4096 + wslot); \
    _Pragma("unroll") for (int q = 0; q < 4; ++q) \
        glds16(bH + bIdxS[q] + GOFF(C), Lc + (P)*32768 + 16384 + q*4096 + wslot); }

    // prologue: 2 chunks in flight (16 glds/wave outstanding)
    STAGE(0, 0);
    STAGE(1, 1);

#pragma unroll
    for (int kk = 0; kk < 25; ++kk) {
        const int P = kk & 1;

        // counted wait: own 8 loads for buf[P] done; next chunk's 8 stay in flight
        if (kk < 24) asm volatile("s_waitcnt vmcnt(8)" ::: "memory");
        else         asm volatile("s_waitcnt vmcnt(0)" ::: "memory");
        __builtin_amdgcn_s_barrier();   // all waves' buf[P] loads landed
        asm volatile("" ::: "memory");

        // MFMA on buf[P]
        __builtin_amdgcn_s_setprio(1);
#pragma unroll
        for (int s = 0; s < 2; ++s) {
            const int rAs = s ? rA1 : rA0;
            const int rBs = s ? rB1 : rB0;
            s16x8 af[4], bfr[4];
#pragma unroll
            for (int i = 0; i < 4; ++i)
                af[i] = *(const s16x8*)(Lc + rAs + i*2048 + P*32768);
#pragma unroll
            for (int j = 0; j < 4; ++j)
                bfr[j] = *(const s16x8*)(Lc + rBs + j*2048 + P*32768);
#pragma unroll
            for (int i = 0; i < 4; ++i)
#pragma unroll
                for (int j = 0; j < 4; ++j)
                    acc[i][j] = __builtin_amdgcn_mfma_f32_16x16x32_bf16(af[i], bfr[j], acc[i][j], 0, 0, 0);
        }
        __builtin_amdgcn_s_setprio(0);

        asm volatile("" ::: "memory");
        __builtin_amdgcn_s_barrier();   // all waves done reading buf[P]
        asm volatile("" ::: "memory");

        // refill buf[P] with chunk kk+2 (no waitcnt — stays in flight)
        if (kk + 2 < 25) { STAGE(kk + 2, P); }
    }

    // ---- epilogue: (dot - K*m2*m1) * is2 * is1 ----
    float m1v[4], is1v[4];
#pragma unroll
    for (int j = 0; j < 4; ++j) {
        int n = n0 + wn*64 + j*16 + fr;
        int nc = n > P1N-1 ? P1N-1 : n;
        m1v[j]  = meanArr[NP2 + b*P1N + nc];
        is1v[j] = invstdArr[NP2 + b*P1N + nc];
    }
#pragma unroll
    for (int i = 0; i < 4; ++i) {
#pragma unroll
        for (int r = 0; r < 4; ++r) {
            int m = m0 + wm*64 + i*16 + fh*4 + r;
            if (m >= P2N) continue;
            float m2  = meanArr[b*P2N + m];
            float is2 = invstdArr[b*P2N + m];
            size_t obase = ((size_t)b*P2N + m) * P1N;
#pragma unroll
            for (int j = 0; j < 4; ++j) {
                int n = n0 + wn*64 + j*16 + fr;
                if (n >= P1N) continue;
                out[obase + n] = (acc[i][j][r] - (float)KF * m2 * m1v[j]) * is2 * is1v[j];
            }
        }
    }
#undef GOFF
#undef STAGE
}

// ---- fallback fp32 corr (128x128 tile; used only if ws too small) ----
__global__ __launch_bounds__(256) void corr_fp32(
    const float* __restrict__ aF, const float* __restrict__ bF,
    const float* __restrict__ meanArr, const float* __restrict__ invstdArr,
    float* __restrict__ out)
{
    __shared__ short As[2][128*64];
    __shared__ short Bs[2][128*64];
    const int b  = blockIdx.z;
    const int m0 = blockIdx.y * 128;
    const int n0 = blockIdx.x * 128;
    const int t  = threadIdx.x;
    const int lane = t & 63;
    const int wid  = t >> 6;
    const int wm = wid >> 1, wn = wid & 1;
    const int fr = lane & 15, fh = lane >> 4;
    const int rsub = t >> 3, c16 = t & 7;
    const int colElem = c16 * 8;
    const int swz = (rsub & 7) << 4;
    const int wByte = rsub*128 + c16*16;

    int aOff[4], bOff[4];
#pragma unroll
    for (int q = 0; q < 4; ++q) {
        int ma = m0 + rsub + 32*q; if (ma > P2N-1) ma = P2N-1;
        int y = ma / OUTC, x = ma % OUTC;
        aOff[q] = ((b*HH + y)*WW + x)*CC;
        int nb = n0 + rsub + 32*q; if (nb > P1N-1) nb = P1N-1;
        int yy = (nb / P1C)*2, xx = (nb % P1C)*2;
        bOff[q] = ((b*HH + yy)*WW + xx)*CC;
    }
    f32x4 acc[4][4];
#pragma unroll
    for (int i = 0; i < 4; ++i)
#pragma unroll
        for (int j = 0; j < 4; ++j) acc[i][j] = (f32x4){0.f,0.f,0.f,0.f};

    f32x4 avF[4][2], bvF[4][2];
#pragma unroll
    for (int q = 0; q < 4; ++q) {
        avF[q][0] = *(const f32x4*)(aF + aOff[q] + colElem);
        avF[q][1] = *(const f32x4*)(aF + aOff[q] + colElem + 4);
        bvF[q][0] = *(const f32x4*)(bF + bOff[q] + colElem);
        bvF[q][1] = *(const f32x4*)(bF + bOff[q] + colElem + 4);
    }
    {
        char* AsB = (char*)As[0]; char* BsB = (char*)Bs[0];
#pragma unroll
        for (int q = 0; q < 4; ++q) {
            u32x4 va = { pack2_bf16(avF[q][0].x, avF[q][0].y), pack2_bf16(avF[q][0].z, avF[q][0].w),
                         pack2_bf16(avF[q][1].x, avF[q][1].y), pack2_bf16(avF[q][1].z, avF[q][1].w) };
            u32x4 vb = { pack2_bf16(bvF[q][0].x, bvF[q][0].y), pack2_bf16(bvF[q][0].z, bvF[q][0].w),
                         pack2_bf16(bvF[q][1].x, bvF[q][1].y), pack2_bf16(bvF[q][1].z, bvF[q][1].w) };
            *(u32x4*)(AsB + ((wByte + q*4096) ^ swz)) = va;
            *(u32x4*)(BsB + ((wByte + q*4096) ^ swz)) = vb;
        }
    }
    for (int kk = 0; kk < 25; ++kk) {
        __syncthreads();
        if (kk < 24) {
            int kn = kk + 1;
            int goff = ((kn/5)*WW + (kn%5))*CC + colElem;
#pragma unroll
            for (int q = 0; q < 4; ++q) {
                avF[q][0] = *(const f32x4*)(aF + aOff[q] + goff);
                avF[q][1] = *(const f32x4*)(aF + aOff[q] + goff + 4);
                bvF[q][0] = *(const f32x4*)(bF + bOff[q] + goff);
                bvF[q][1] = *(const f32x4*)(bF + bOff[q] + goff + 4);
            }
        }
        {
            const char* AsB = (const char*)As[kk & 1];
            const char* BsB = (const char*)Bs[kk & 1];
#pragma unroll
            for (int step = 0; step < 2; ++step) {
                s16x8 af[4], bfr[4];
#pragma unroll
                for (int i = 0; i < 4; ++i) {
                    int row = wm*64 + i*16 + fr;
                    af[i] = *(const s16x8*)(AsB + ((row*128 + step*64 + fh*16) ^ ((fr & 7) << 4)));
                }
#pragma unroll
                for (int j = 0; j < 4; ++j) {
                    int row = wn*64 + j*16 + fr;
                    bfr[j] = *(const s16x8*)(BsB + ((row*128 + step*64 + fh*16) ^ ((fr & 7) << 4)));
                }
#pragma unroll
                for (int i = 0; i < 4; ++i)
#pragma unroll
                    for (int j = 0; j < 4; ++j)
                        acc[i][j] = __builtin_amdgcn_mfma_f32_16x16x32_bf16(af[i], bfr[j], acc[i][j], 0, 0, 0);
            }
        }
        if (kk < 24) {
            char* AsB = (char*)As[(kk + 1) & 1];
            char* BsB = (char*)Bs[(kk + 1) & 1];
#pragma unroll
            for (int q = 0; q < 4; ++q) {
                u32x4 va = { pack2_bf16(avF[q][0].x, avF[q][0].y), pack2_bf16(avF[q][0].z, avF[q][0].w),
                             pack2_bf16(avF[q][1].x, avF[q][1].y), pack2_bf16(avF[q][1].z, avF[q][1].w) };
                u32x4 vb = { pack2_bf16(bvF[q][0].x, bvF[q][0].y), pack2_bf16(bvF[q][0].z, bvF[q][0].w),
                             pack2_bf16(bvF[q][1].x, bvF[q][1].y), pack2_bf16(bvF[q][1].z, bvF[q][1].w) };
                *(u32x4*)(AsB + ((wByte + q*4096) ^ swz)) = va;
                *(u32x4*)(BsB + ((wByte + q*4096) ^ swz)) = vb;
            }
        }
    }
    float m1v[4], is1v[4];
#pragma unroll
    for (int j = 0; j < 4; ++j) {
        int n = n0 + wn*64 + j*16 + fr;
        int nc = n > P1N-1 ? P1N-1 : n;
        m1v[j]  = meanArr[NP2 + b*P1N + nc];
        is1v[j] = invstdArr[NP2 + b*P1N + nc];
    }
#pragma unroll
    for (int i = 0; i < 4; ++i) {
#pragma unroll
        for (int r = 0; r < 4; ++r) {
            int m = m0 + wm*64 + i*16 + fh*4 + r;
            if (m >= P2N) continue;
            float m2  = meanArr[b*P2N + m];
            float is2 = invstdArr[b*P2N + m];
            size_t obase = ((size_t)b*P2N + m) * P1N;
#pragma unroll
            for (int j = 0; j < 4; ++j) {
                int n = n0 + wn*64 + j*16 + fr;
                if (n >= P1N) continue;
                out[obase + n] = (acc[i][j][r] - (float)KF * m2 * m1v[j]) * is2 * is1v[j];
            }
        }
    }
}

extern "C" void kernel_launch(void* const* d_in, const int* in_sizes, int n_in,
                              void* d_out, int out_size, void* d_ws, size_t ws_size,
                              hipStream_t stream) {
    const float* in1 = (const float*)d_in[0];   // strided patches -> N side
    const float* in2 = (const float*)d_in[1];   // dense patches   -> M side
    float* out = (float*)d_out;

    float* meanArr   = (float*)d_ws;
    float* invstdArr = meanArr + (NP2 + NP1);
    float* pS1 = invstdArr + (NP2 + NP1);
    float* pQ1 = pS1 + NPIX;
    float* pS2 = pQ1 + NPIX;
    float* pQ2 = pS2 + NPIX;
    short* b1 = (short*)(pQ2 + NPIX);           // bf16 input_1
    short* b2 = b1 + NELEM;                     // bf16 input_2
    size_t need = (size_t)((char*)(b2 + NELEM) - (char*)d_ws);
    bool useBf16 = (ws_size >= need);

    if (useBf16) {
        // grid: batch FASTEST -> flat_id % 8 == batch == XCD (L2 affinity)
        dim3 grid(NB, (P1N + BN - 1) / BN, (P2N + BM - 1) / BM);   // 8 x 4 x 14 = 448
        cvt_pix<<<NELEM/4/256, 256, 0, stream>>>(in1, in2, (u32*)b1, (u32*)b2,
                                                 pS1, pQ1, pS2, pQ2);
        pstats<<<(NP2 + NP1 + 255)/256, 256, 0, stream>>>(pS1, pQ1, pS2, pQ2,
                                                          meanArr, invstdArr);
        corr_mfma_bf16<<<grid, 256, 0, stream>>>(b2, b1, meanArr, invstdArr, out);
    } else {
        dim3 gridF((P1N + 127) / 128, (P2N + 127) / 128, NB);
        stats_kernel<<<(NP2 + NP1) / 4, 256, 0, stream>>>(in1, in2, meanArr, invstdArr);
        corr_fp32<<<gridF, 256, 0, stream>>>(in2, in1, meanArr, invstdArr, out);
    }
}